// Round 2
// baseline (648.809 us; speedup 1.0000x reference)
//
#include <hip/hip_runtime.h>
#include <hip/hip_fp16.h>

// DynamicRouting (capsule routing), MI355X / gfx950.
// votes: [B=128, I=2048, O=32, P=4] fp32 (128 MiB). activations_in unused.
// b_ij^(t)[b,i,o] = sum_{tau<t} dot(votes[b,i,o,:], v^tau[b,o,:]) -> b_ij never materialized.
//
// R7 changes vs R6 (641 us; routing_fused 516 us):
//  R6's hv[32] register-vote array was DEMOTED TO SCRATCH: VGPR_Count=64 (the
//  8-waves/EU boundary) + WRITE_SIZE=225 MB (expected ~2 MB) => the backend shrank
//  registers for occupancy and spilled the whole array; every vote round-tripped
//  through scratch (516 us, 2% VALUBusy).
//  Fix:
//   - amdgpu_waves_per_eu(4,4): pin exactly 4 waves/EU => full 128-VGPR budget,
//     no occupancy-driven spilling.
//   - votes held in 32 NAMED uint2 variables (token-pasted macros), not an array
//     => reliably SROA'd into VGPRs (64 VGPRs of fp16 votes per thread).
//  Structure otherwise identical to R6: 1024 blocks (4/CU, fully co-resident),
//  per-b counter barrier (release atomicAdd + acquire spin, agent scope),
//  partials [t][b][chunk][o], finalize in chunk 0. Numerics = R5/R6 (absmax 0.0039).

#define BATCH 128
#define IC 2048
#define OC 32
#define POSE 4
#define REPS 1e-7f
#define CHUNKS 8
#define CHUNK_I (IC / CHUNKS)             // 256 input capsules per block
#define BLOCK_T 256
#define GROUPS (BLOCK_T / 32)             // 8 o-groups per block
#define ILP 4
#define STEPS (CHUNK_I / (GROUPS * ILP))  // 8 steps, 4 i's per thread per step

// partials layout: [t][b][chunk][o] float4
#define PART_IDX(t, b, c, o) ((((size_t)(t) * BATCH + (b)) * CHUNKS + (c)) * OC + (o))

// ---- fp16 pack/unpack (2x __half2 bit-cast through uint2) ----
__device__ __forceinline__ uint2 packh(const float4 v) {
    union { __half2 h; unsigned u; } a, b;
    a.h = __float22half2_rn(make_float2(v.x, v.y));
    b.h = __float22half2_rn(make_float2(v.z, v.w));
    return make_uint2(a.u, b.u);
}
__device__ __forceinline__ float4 unpackh(const uint2 q) {
    union { unsigned u; __half2 h; } a, b;
    a.u = q.x; b.u = q.y;
    const float2 f0 = __half22float2(a.h);
    const float2 f1 = __half22float2(b.h);
    return make_float4(f0.x, f0.y, f1.x, f1.y);
}

__device__ __forceinline__ float dot4(const float4 a, const float4 b) {
    return a.x*b.x + a.y*b.y + a.z*b.z + a.w*b.w;
}

// squash: v = (n2/(1+n2)) * s / sqrt(n2),  n2 = |s|^2 + eps
__device__ __forceinline__ float4 squash4(const float4 s) {
    const float n2 = s.x*s.x + s.y*s.y + s.z*s.z + s.w*s.w + REPS;
    const float f = n2 / (1.f + n2) * rsqrtf(n2);
    return make_float4(f*s.x, f*s.y, f*s.z, f*s.w);
}

// sum the 8 chunk partials for (b,o) of iteration t, apply scale, squash
__device__ __forceinline__ float4 reduce_squash(
    const float4* __restrict__ partials, int t, int b, int o, float scale)
{
    float4 acc = make_float4(0.f, 0.f, 0.f, 0.f);
    #pragma unroll
    for (int c = 0; c < CHUNKS; ++c) {
        const float4 p = partials[PART_IDX(t, b, c, o)];
        acc.x += p.x; acc.y += p.y; acc.z += p.z; acc.w += p.w;
    }
    acc.x *= scale; acc.y *= scale; acc.z *= scale; acc.w *= scale;
    return squash4(acc);
}

// block-reduce 8 group partials per o, write one chunk partial (no atomics)
__device__ __forceinline__ void block_reduce_store(
    float4 s_acc, float4* lds_s, float4* __restrict__ partials,
    int t, int b, int chunk, int g, int o)
{
    lds_s[g * 32 + o] = s_acc;
    __syncthreads();
    if (threadIdx.x < 32) {
        float4 tot = lds_s[o];
        #pragma unroll
        for (int gg = 1; gg < GROUPS; ++gg) {
            const float4 x = lds_s[gg * 32 + o];
            tot.x += x.x; tot.y += x.y; tot.z += x.z; tot.w += x.w;
        }
        partials[PART_IDX(t, b, chunk, o)] = tot;   // 512 B coalesced
    }
}

// per-b barrier: monotonic counter, 8 arrivals per phase.
// __syncthreads drains this block's partial stores (vmcnt(0) before s_barrier);
// __threadfence orders/publishes across XCDs; release add publishes the count.
__device__ __forceinline__ void bar_arrive(unsigned int* cnt) {
    __syncthreads();
    if (threadIdx.x == 0) {
        __threadfence();
        __hip_atomic_fetch_add(cnt, 1u, __ATOMIC_RELEASE, __HIP_MEMORY_SCOPE_AGENT);
    }
}
__device__ __forceinline__ void bar_wait(unsigned int* cnt, unsigned int target) {
    if (threadIdx.x == 0) {
        while (__hip_atomic_load(cnt, __ATOMIC_ACQUIRE, __HIP_MEMORY_SCOPE_AGENT) < target)
            __builtin_amdgcn_s_sleep(2);
        __threadfence();   // invalidate stale lines before the block reads partials
    }
    __syncthreads();
}

// softmax over o (32 lanes) + weighted accumulate for 4 register-resident quads
__device__ __forceinline__ void accum4(const uint2 q0, const uint2 q1,
                                       const uint2 q2, const uint2 q3,
                                       const float4 vh, float4& s_acc)
{
    const float4 v0 = unpackh(q0);
    const float4 v1 = unpackh(q1);
    const float4 v2 = unpackh(q2);
    const float4 v3 = unpackh(q3);

    const float l0 = dot4(v0, vh);
    const float l1 = dot4(v1, vh);
    const float l2 = dot4(v2, vh);
    const float l3 = dot4(v3, vh);
    // no max-subtraction: |logit| <~ 8 (|vh|<2, votes ~ N(0,1)) -> fp32 exp safe
    float e0 = __expf(l0), e1 = __expf(l1), e2 = __expf(l2), e3 = __expf(l3);
    float t0 = e0, t1 = e1, t2 = e2, t3 = e3;
    // butterfly sums over the 32-lane o-group; 4 independent chains interleave
    #pragma unroll
    for (int d = 16; d >= 1; d >>= 1) {
        t0 += __shfl_xor(t0, d);
        t1 += __shfl_xor(t1, d);
        t2 += __shfl_xor(t2, d);
        t3 += __shfl_xor(t3, d);
    }
    const float c0 = e0 * __builtin_amdgcn_rcpf(t0);
    const float c1 = e1 * __builtin_amdgcn_rcpf(t1);
    const float c2 = e2 * __builtin_amdgcn_rcpf(t2);
    const float c3 = e3 * __builtin_amdgcn_rcpf(t3);

    s_acc.x += c0*v0.x + c1*v1.x + c2*v2.x + c3*v3.x;
    s_acc.y += c0*v0.y + c1*v1.y + c2*v2.y + c3*v3.y;
    s_acc.z += c0*v0.z + c1*v1.z + c2*v2.z + c3*v3.z;
    s_acc.w += c0*v0.w + c1*v1.w + c2*v2.w + c3*v3.w;
}

__global__ void routing_init(unsigned int* __restrict__ counters) {
    if (threadIdx.x < BATCH) counters[threadIdx.x * 32] = 0;  // one 128B line per b
}

// named-variable vote storage: 32 uint2 per thread (64 VGPRs), never an array
#define DECL_STEP(s) uint2 q##s##_0, q##s##_1, q##s##_2, q##s##_3
#define SADD(v) { s0.x += (v).x; s0.y += (v).y; s0.z += (v).z; s0.w += (v).w; }
#define LOAD_STEP(s) do {                                                   \
    const float4* vp = vb + (size_t)(i0 + (s) * (GROUPS * ILP) + g) * OC + o; \
    float4 v;                                                               \
    v = vp[0 * GROUPS * OC]; SADD(v); q##s##_0 = packh(v);                  \
    v = vp[1 * GROUPS * OC]; SADD(v); q##s##_1 = packh(v);                  \
    v = vp[2 * GROUPS * OC]; SADD(v); q##s##_2 = packh(v);                  \
    v = vp[3 * GROUPS * OC]; SADD(v); q##s##_3 = packh(v);                  \
} while (0)
#define ACC_STEP(s, vh, sa) accum4(q##s##_0, q##s##_1, q##s##_2, q##s##_3, (vh), (sa))

__global__ __launch_bounds__(BLOCK_T)
__attribute__((amdgpu_waves_per_eu(4, 4)))   // pin 4 waves/EU: full 128-VGPR budget,
                                             // no occupancy-driven spill (R6 bug)
void routing_fused(
    const float4* __restrict__ votes,
    float* __restrict__ out,             // poses [B,O,P] then acts [B,O,1]
    unsigned int* __restrict__ counters,
    float4* __restrict__ partials)
{
    const int blk   = blockIdx.x;
    const int b     = blk >> 3;                 // CHUNKS=8
    const int chunk = blk & (CHUNKS - 1);
    const int o     = threadIdx.x & 31;
    const int g     = threadIdx.x >> 5;
    unsigned int* cnt = counters + (size_t)b * 32;

    __shared__ float4 lds_s[GROUPS * 32];
    __shared__ float4 vh_s[32];

    DECL_STEP(0); DECL_STEP(1); DECL_STEP(2); DECL_STEP(3);
    DECL_STEP(4); DECL_STEP(5); DECL_STEP(6); DECL_STEP(7);

    const float4* vb = votes + (size_t)b * IC * OC;
    const int i0 = chunk * CHUNK_I;

    // ---- t=0: stream fp32 votes once, keep fp16 in named regs, mean-reduce ----
    float4 s0 = make_float4(0.f, 0.f, 0.f, 0.f);
    LOAD_STEP(0); LOAD_STEP(1); LOAD_STEP(2); LOAD_STEP(3);
    LOAD_STEP(4); LOAD_STEP(5); LOAD_STEP(6); LOAD_STEP(7);
    // softmax(0) == 1/32 uniform; 1/32 applied at the reduce
    block_reduce_store(s0, lds_s, partials, 0, b, chunk, g, o);
    bar_arrive(cnt);
    bar_wait(cnt, 1 * CHUNKS);

    // ---- t=1 ----
    if (threadIdx.x < 32)
        vh_s[o] = reduce_squash(partials, 0, b, o, 1.f / 32.f);
    __syncthreads();
    const float4 vh0 = vh_s[o];                 // keep v^0 for t=2 (no re-reduce)

    float4 s1 = make_float4(0.f, 0.f, 0.f, 0.f);
    ACC_STEP(0, vh0, s1); ACC_STEP(1, vh0, s1);
    ACC_STEP(2, vh0, s1); ACC_STEP(3, vh0, s1);
    ACC_STEP(4, vh0, s1); ACC_STEP(5, vh0, s1);
    ACC_STEP(6, vh0, s1); ACC_STEP(7, vh0, s1);
    block_reduce_store(s1, lds_s, partials, 1, b, chunk, g, o);
    bar_arrive(cnt);
    bar_wait(cnt, 2 * CHUNKS);

    // ---- t=2: logit = dot(v, vh0) + dot(v, vh1) == dot(v, vh0+vh1) ----
    if (threadIdx.x < 32)
        vh_s[o] = reduce_squash(partials, 1, b, o, 1.f);
    __syncthreads();
    float4 vh01 = vh_s[o];
    vh01.x += vh0.x; vh01.y += vh0.y; vh01.z += vh0.z; vh01.w += vh0.w;

    float4 s2 = make_float4(0.f, 0.f, 0.f, 0.f);
    ACC_STEP(0, vh01, s2); ACC_STEP(1, vh01, s2);
    ACC_STEP(2, vh01, s2); ACC_STEP(3, vh01, s2);
    ACC_STEP(4, vh01, s2); ACC_STEP(5, vh01, s2);
    ACC_STEP(6, vh01, s2); ACC_STEP(7, vh01, s2);
    block_reduce_store(s2, lds_s, partials, 2, b, chunk, g, o);
    bar_arrive(cnt);

    // ---- finalize: chunk 0 of each b reduces + writes its 32 outputs ----
    if (chunk == 0) {
        bar_wait(cnt, 3 * CHUNKS);
        if (threadIdx.x < 32) {
            const float4 v = reduce_squash(partials, 2, b, o, 1.f);
            ((float4*)out)[b * OC + o] = v;                            // poses_out
            const float a = sqrtf(v.x*v.x + v.y*v.y + v.z*v.z + v.w*v.w + REPS);
            out[BATCH * OC * POSE + b * OC + o] = a;                   // activations
        }
    }
}

extern "C" void kernel_launch(void* const* d_in, const int* in_sizes, int n_in,
                              void* d_out, int out_size, void* d_ws, size_t ws_size,
                              hipStream_t stream) {
    const float4* votes = (const float4*)d_in[0];
    // d_in[1] (activations_in) unused by the reference.

    // ws layout: counters (16 KiB, one 128B line per b) | partials (1.5 MiB)
    unsigned int* counters = (unsigned int*)d_ws;
    float4* partials = (float4*)((char*)d_ws + 16 * 1024);

    routing_init<<<1, 128, 0, stream>>>(counters);
    routing_fused<<<BATCH * CHUNKS, BLOCK_T, 0, stream>>>(
        votes, (float*)d_out, counters, partials);
}